// Round 8
// baseline (227.438 us; speedup 1.0000x reference)
//
#include <hip/hip_runtime.h>
#include <math.h>

#define SS 64
#define BB 32
#define DD 586
#define DE 583      // emb columns
#define U1 114      // length after conv1+pool1
#define U2 38       // after pool2
#define T3 36       // conv3 out length
#define NTOK 18752  // B*D elements per s
#define NSTAT (SS*BB)
#define SQD 24.207436873820409f  // sqrt(586)

// ws layout:
//   double rowsumd[2048]; double rowsqd[2048];
//   float  part[4][64][16][114];   // raw conv1+pool1 partials (no affine)
//   int    counter[64];            // per-s arrival counter (memset to 0)

// Single fused kernel, grid (s=64, g=4), 256 threads.
//  Phase 1 (all blocks): gather 8 rows once -> LDS; per-row double stats ->
//    ws; raw fused conv1+avgpool(5) in xw-form -> part. wlb/blb/wsumb
//    preloaded concurrently (overlaps gather latency).
//  Phase 2 (last-arriving block per s): acquire, reduce stats -> affine,
//    assemble o2 = al*sum(part) + de*wsum + b1, pool2/conv2/conv3/dense/
//    argmax. Math identical to R6's absmax-0 chain.
__global__ __launch_bounds__(256) void k_fused(
    const int* __restrict__ tokens, const float* __restrict__ emb,
    const float* __restrict__ pos, const float* __restrict__ gamma,
    const float* __restrict__ beta, const float* __restrict__ w1,
    const float* __restrict__ b1, const float* __restrict__ w2,
    const float* __restrict__ b2, const float* __restrict__ w3,
    const float* __restrict__ b3, const float* __restrict__ wl,
    const float* __restrict__ bl,
    double* __restrict__ rowsumd, double* __restrict__ rowsqd,
    float* __restrict__ part, int* __restrict__ counter,
    float* __restrict__ out)
{
  const int s = blockIdx.x, g = blockIdx.y;
  const int tid = threadIdx.x;
  __shared__ float xs[8*DD];
  __shared__ float wlb[128*37];   // +1 pad: conflict-free
  __shared__ float blb[128];
  __shared__ float wsumb[16];
  __shared__ int stok[8];
  __shared__ int isLast;
  __shared__ float sAl, sDe;
  __shared__ float o2[16*U1];
  __shared__ float p2[16*U2];
  __shared__ float o4[8*U2];
  __shared__ float o5[32*T3];

  if (tid < 8) stok[tid] = tokens[s*BB + g*8 + tid];
  // speculative tail-weight preload (all blocks; overlaps gather latency)
  for (int idx = tid; idx < 128*36; idx += 256) {
    int v = idx / 36, t = idx - v*36;
    wlb[v*37 + t] = wl[idx];
  }
  if (tid < 128) blb[tid] = bl[tid];
  {  // wsum[o] = sum of 544 contiguous w1 floats
    const int o = tid >> 4, i = tid & 15;
    float acc = 0.f;
    for (int j = i; j < BB*17; j += 16) acc += w1[o*BB*17 + j];
    for (int off = 8; off > 0; off >>= 1) acc += __shfl_down(acc, off, 16);
    if (i == 0) wsumb[o] = acc;
  }
  __syncthreads();

  // ---- gather once: row rr = tid>>5 (8 rows x 32 lanes) ----
  {
    const int rr = tid >> 5, l = tid & 31;
    const float* row = emb + (size_t)stok[rr]*DE;
    double sum = 0.0, sq = 0.0;
    #pragma unroll
    for (int j = 0; j < 19; ++j) {
      int d = l + 32*j;
      if (d < DD) {
        float v = (d < DE) ? row[d] * SQD
                           : pos[(s*BB + g*8 + rr)*3 + (d - DE)];
        xs[rr*DD + d] = v;
        sum += v; sq += (double)v*v;
      }
    }
    for (int off = 16; off > 0; off >>= 1) {
      sum += __shfl_down(sum, off, 32);
      sq  += __shfl_down(sq, off, 32);
    }
    if (l == 0) {
      rowsumd[s*BB + g*8 + rr] = sum;
      rowsqd [s*BB + g*8 + rr] = sq;
    }
  }
  __syncthreads();

  // ---- raw conv1+pool1, xw-form: up=tid&127 -> u, oh=tid>>7 ----
  const int up = tid & 127;
  const int oh = __builtin_amdgcn_readfirstlane(tid >> 7);
  const int u  = (up < U1) ? up : (U1 - 1);
  float acc[8] = {0,0,0,0,0,0,0,0};
  for (int cc = 0; cc < 8; ++cc) {
    const float* xr = &xs[cc*DD + 5*u];   // stride-5: conflict-free
    float xv[21];
    #pragma unroll
    for (int m = 0; m < 21; ++m) xv[m] = xr[m];
    float xw[17];
    #pragma unroll
    for (int k = 0; k < 17; ++k)
      xw[k] = ((xv[k] + xv[k+1]) + (xv[k+2] + xv[k+3])) + xv[k+4];
    #pragma unroll
    for (int j = 0; j < 8; ++j) {
      const float* wj = w1 + ((size_t)(oh*8 + j)*BB + (g*8 + cc))*17;
      float a = 0.f;
      #pragma unroll
      for (int k = 0; k < 17; ++k) a += xw[k] * wj[k];
      acc[j] += a;
    }
  }
  if (up < U1) {
    float* pb = part + ((size_t)(g*SS + s)*16 + oh*8)*U1 + up;
    #pragma unroll
    for (int j = 0; j < 8; ++j) pb[j*U1] = acc[j] * 0.2f;  // coalesced
  }

  // ---- arrival protocol: last of the 4 (s,*) blocks runs the tail ----
  __threadfence();   // release: part/rowsum writes visible device-wide
  __syncthreads();
  if (tid == 0) {
    int old = __hip_atomic_fetch_add(&counter[s], 1, __ATOMIC_ACQ_REL,
                                     __HIP_MEMORY_SCOPE_AGENT);
    isLast = (old == 3);
  }
  __syncthreads();
  if (!isLast) return;
  __threadfence();   // acquire: see other blocks' part/rowsum writes

  // ---- tail (identical math to R6 k_tail) ----
  if (tid < 32) {
    double sm = rowsumd[s*BB + tid], qq = rowsqd[s*BB + tid];
    for (int off = 16; off > 0; off >>= 1) {
      sm += __shfl_down(sm, off, 32);
      qq += __shfl_down(qq, off, 32);
    }
    if (tid == 0) {
      double m0d = sm / (double)NTOK;
      float m0 = (float)m0d;
      float v0 = (float)(qq / (double)NTOK - m0d*m0d);
      float a = 1.0f;
      for (int l = 0; l < 4; ++l) {
        float r = 1.0f / sqrtf(a*a*v0 + 1e-5f);
        a = gamma[l*SS + s] * r * a;
      }
      sAl = a;
      sDe = beta[3*SS + s] - a*m0;
    }
  }
  __syncthreads();
  const float al = sAl, de = sDe;
  for (int idx = tid; idx < 16*U1; idx += 256) {
    int o = idx / U1;
    float psum = part[(size_t)(0*SS + s)*16*U1 + idx]
               + part[(size_t)(1*SS + s)*16*U1 + idx]
               + part[(size_t)(2*SS + s)*16*U1 + idx]
               + part[(size_t)(3*SS + s)*16*U1 + idx];
    o2[idx] = al*psum + de*wsumb[o] + b1[o];
  }
  __syncthreads();
  for (int i2 = tid; i2 < 16*U2; i2 += 256) {   // 608 > 256: loop required
    int o = i2 / U2, v = i2 - o*U2;
    p2[i2] = (o2[o*U1 + 3*v] + o2[o*U1 + 3*v+1] + o2[o*U1 + 3*v+2]) * (1.f/3.f);
  }
  __syncthreads();
  for (int i2 = tid; i2 < 8*U2; i2 += 256) {    // 304 > 256: loop required
    int p = i2 / U2, v = i2 - p*U2;
    float a2 = b2[p];
    #pragma unroll
    for (int o = 0; o < 16; ++o) a2 += p2[o*U2 + v] * w2[p*16 + o];
    o4[i2] = a2;
  }
  __syncthreads();
  for (int i2 = tid; i2 < 32*T3; i2 += 256) {   // 1152 > 256: loop required
    int q = i2 / T3, t = i2 - q*T3;
    float a3 = b3[q];
    #pragma unroll
    for (int p = 0; p < 8; ++p) {
      a3 += o4[p*U2 + t    ] * w3[(q*8+p)*3 + 0]
          + o4[p*U2 + t + 1] * w3[(q*8+p)*3 + 1]
          + o4[p*U2 + t + 2] * w3[(q*8+p)*3 + 2];
    }
    o5[i2] = a3;
  }
  __syncthreads();
  // q = tid>>3 covers 0..31, vs = tid&7; v ascending per thread;
  // (max,min-idx) merge preserves first-max tie-break.
  const int q = tid >> 3, vs = tid & 7;
  float best = -1e30f; int bidx = 0;
  const float* orow = &o5[q*T3];
  for (int i = 0; i < 16; ++i) {
    int v = vs + 8*i;
    float a4 = blb[v];
    const float* wr = &wlb[v*37];
    #pragma unroll
    for (int t = 0; t < 36; ++t) a4 += orow[t] * wr[t];
    if (a4 > best) { best = a4; bidx = v; }
  }
  #pragma unroll
  for (int off = 1; off < 8; off <<= 1) {
    float ov = __shfl_xor(best, off);
    int oi = __shfl_xor(bidx, off);
    if (ov > best || (ov == best && oi < bidx)) { best = ov; bidx = oi; }
  }
  if (vs == 0) out[s*BB + q] = (float)bidx;
}

extern "C" void kernel_launch(void* const* d_in, const int* in_sizes, int n_in,
                              void* d_out, int out_size, void* d_ws, size_t ws_size,
                              hipStream_t stream)
{
  const int*   tokens = (const int*)  d_in[0];
  const float* emb    = (const float*)d_in[1];
  const float* pos    = (const float*)d_in[2];
  const float* gamma  = (const float*)d_in[3];
  const float* beta   = (const float*)d_in[4];
  const float* w1     = (const float*)d_in[5];
  const float* b1     = (const float*)d_in[6];
  const float* w2     = (const float*)d_in[7];
  const float* b2     = (const float*)d_in[8];
  const float* w3     = (const float*)d_in[9];
  const float* b3     = (const float*)d_in[10];
  const float* wl     = (const float*)d_in[11];
  const float* bl     = (const float*)d_in[12];
  float* out = (float*)d_out;

  double* rowsumd = (double*)d_ws;            // 2048
  double* rowsqd  = rowsumd + NSTAT;          // 2048
  float*  part    = (float*)(rowsqd + NSTAT); // 4*64*16*114
  int*    counter = (int*)(part + 4*SS*16*U1);// 64

  (void)hipMemsetAsync(counter, 0, SS*sizeof(int), stream);
  k_fused<<<dim3(SS, 4), dim3(256), 0, stream>>>(
      tokens, emb, pos, gamma, beta, w1, b1, w2, b2, w3, b3, wl, bl,
      rowsumd, rowsqd, part, counter, out);
}

// Round 9
// 205.508 us; speedup vs baseline: 1.1067x; 1.1067x over previous
//
#include <hip/hip_runtime.h>
#include <math.h>

#define SS 64
#define BB 32
#define DD 586
#define DE 583      // emb columns
#define U1 114      // length after conv1+pool1
#define U2 38       // after pool2
#define T3 36       // conv3 out length
#define NTOK 18752  // B*D elements per s
#define NSTAT (SS*BB)
#define SQD 24.207436873820409f  // sqrt(586)

// ws layout:
//   double rowsumd[2048]; double rowsqd[2048];
//   float  part[4][64][16][114];   // raw conv1+pool1 partials (no affine)

// ---- K1: gather once -> row stats + raw fused conv1+avgpool(5) ----
// (identical to R6's proven k_main)
__global__ __launch_bounds__(256) void k_main(
    const int* __restrict__ tokens, const float* __restrict__ emb,
    const float* __restrict__ pos, const float* __restrict__ w1,
    double* __restrict__ rowsumd, double* __restrict__ rowsqd,
    float* __restrict__ part)
{
  const int s = blockIdx.x, g = blockIdx.y;
  const int tid = threadIdx.x;
  __shared__ float xs[8*DD];
  __shared__ int stok[8];
  if (tid < 8) stok[tid] = tokens[s*BB + g*8 + tid];
  __syncthreads();
  {
    const int rr = tid >> 5, l = tid & 31;
    const float* row = emb + (size_t)stok[rr]*DE;
    double sum = 0.0, sq = 0.0;
    #pragma unroll
    for (int j = 0; j < 19; ++j) {
      int d = l + 32*j;
      if (d < DD) {
        float v = (d < DE) ? row[d] * SQD
                           : pos[(s*BB + g*8 + rr)*3 + (d - DE)];
        xs[rr*DD + d] = v;
        sum += v; sq += (double)v*v;
      }
    }
    for (int off = 16; off > 0; off >>= 1) {
      sum += __shfl_down(sum, off, 32);
      sq  += __shfl_down(sq, off, 32);
    }
    if (l == 0) {
      rowsumd[s*BB + g*8 + rr] = sum;
      rowsqd [s*BB + g*8 + rr] = sq;
    }
  }
  __syncthreads();
  const int up = tid & 127;
  const int oh = __builtin_amdgcn_readfirstlane(tid >> 7);  // wave-uniform
  const int u  = (up < U1) ? up : (U1 - 1);
  float acc[8] = {0,0,0,0,0,0,0,0};
  for (int cc = 0; cc < 8; ++cc) {
    const float* xr = &xs[cc*DD + 5*u];   // stride-5: conflict-free
    float xv[21];
    #pragma unroll
    for (int m = 0; m < 21; ++m) xv[m] = xr[m];
    float xw[17];
    #pragma unroll
    for (int k = 0; k < 17; ++k)
      xw[k] = ((xv[k] + xv[k+1]) + (xv[k+2] + xv[k+3])) + xv[k+4];
    #pragma unroll
    for (int j = 0; j < 8; ++j) {
      const float* wj = w1 + ((size_t)(oh*8 + j)*BB + (g*8 + cc))*17;
      float a = 0.f;
      #pragma unroll
      for (int k = 0; k < 17; ++k) a += xw[k] * wj[k];
      acc[j] += a;
    }
  }
  if (up < U1) {
    float* pb = part + ((size_t)(g*SS + s)*16 + oh*8)*U1 + up;
    #pragma unroll
    for (int j = 0; j < 8; ++j) pb[j*U1] = acc[j] * 0.2f;  // coalesced
  }
}

// ---- K2: stats -> affine assembly, pool2, conv2, conv3, dense, argmax ----
// Dense rewritten: o5 row in VGPRs + wave-uniform scalar wl/bl loads
// (zero LDS traffic in the dense loop; same t-ascending fma chain).
__global__ __launch_bounds__(256) void k_tail(
    const double* __restrict__ rowsumd, const double* __restrict__ rowsqd,
    const float* __restrict__ gamma, const float* __restrict__ beta,
    const float* __restrict__ part, const float* __restrict__ w1,
    const float* __restrict__ b1, const float* __restrict__ w2,
    const float* __restrict__ b2, const float* __restrict__ w3,
    const float* __restrict__ b3, const float* __restrict__ wl,
    const float* __restrict__ bl, float* __restrict__ out)
{
  const int s = blockIdx.x, tid = threadIdx.x;
  __shared__ float o2[16*U1];
  __shared__ float p2[16*U2];
  __shared__ float o4[8*U2];
  __shared__ float o5[32*T3];
  __shared__ float wsumb[16];
  __shared__ float sAl, sDe;
  __shared__ float candv[4][32];
  __shared__ int   candi[4][32];
  // wsum[o] = sum of 544 contiguous w1 floats
  {
    const int o = tid >> 4, i = tid & 15;
    float acc = 0.f;
    for (int j = i; j < BB*17; j += 16) acc += w1[o*BB*17 + j];
    for (int off = 8; off > 0; off >>= 1) acc += __shfl_down(acc, off, 16);
    if (i == 0) wsumb[o] = acc;
  }
  // deterministic stats reduce (32 doubles, fixed tree) -> al, de
  if (tid < 32) {
    double sm = rowsumd[s*BB + tid], qq = rowsqd[s*BB + tid];
    for (int off = 16; off > 0; off >>= 1) {
      sm += __shfl_down(sm, off, 32);
      qq += __shfl_down(qq, off, 32);
    }
    if (tid == 0) {
      double m0d = sm / (double)NTOK;
      float m0 = (float)m0d;
      float v0 = (float)(qq / (double)NTOK - m0d*m0d);
      float a = 1.0f;
      for (int l = 0; l < 4; ++l) {
        float r = 1.0f / sqrtf(a*a*v0 + 1e-5f);
        a = gamma[l*SS + s] * r * a;
      }
      sAl = a;
      sDe = beta[3*SS + s] - a*m0;
    }
  }
  __syncthreads();
  const float al = sAl, de = sDe;
  for (int idx = tid; idx < 16*U1; idx += 256) {
    int o = idx / U1;
    float psum = part[(size_t)(0*SS + s)*16*U1 + idx]
               + part[(size_t)(1*SS + s)*16*U1 + idx]
               + part[(size_t)(2*SS + s)*16*U1 + idx]
               + part[(size_t)(3*SS + s)*16*U1 + idx];
    o2[idx] = al*psum + de*wsumb[o] + b1[o];
  }
  __syncthreads();
  for (int i2 = tid; i2 < 16*U2; i2 += 256) {   // 608 > 256: loop required
    int o = i2 / U2, v = i2 - o*U2;
    p2[i2] = (o2[o*U1 + 3*v] + o2[o*U1 + 3*v+1] + o2[o*U1 + 3*v+2]) * (1.f/3.f);
  }
  __syncthreads();
  for (int i2 = tid; i2 < 8*U2; i2 += 256) {    // 304 > 256: loop required
    int p = i2 / U2, v = i2 - p*U2;
    float a2 = b2[p];
    #pragma unroll
    for (int o = 0; o < 16; ++o) a2 += p2[o*U2 + v] * w2[p*16 + o];
    o4[i2] = a2;
  }
  __syncthreads();
  for (int i2 = tid; i2 < 32*T3; i2 += 256) {   // 1152 > 256: loop required
    int q = i2 / T3, t = i2 - q*T3;
    float a3 = b3[q];
    #pragma unroll
    for (int p = 0; p < 8; ++p) {
      a3 += o4[p*U2 + t    ] * w3[(q*8+p)*3 + 0]
          + o4[p*U2 + t + 1] * w3[(q*8+p)*3 + 1]
          + o4[p*U2 + t + 2] * w3[(q*8+p)*3 + 2];
    }
    o5[i2] = a3;
  }
  __syncthreads();
  // dense + argmax: wave w covers v in [32w, 32w+32) ascending; lane q=l&31
  // holds its o5 row in registers; wl/bl via wave-uniform scalar loads.
  // Halves h=0/1 compute redundantly (keeps v wave-uniform); h=0 publishes.
  {
    const int w = __builtin_amdgcn_readfirstlane(tid >> 6);
    const int lane = tid & 63;
    const int q = lane & 31;
    float orow[T3];
    #pragma unroll
    for (int t = 0; t < T3; ++t) orow[t] = o5[q*T3 + t];
    float best = -1e30f; int bidx = 0;
    #pragma unroll
    for (int j = 0; j < 16; ++j) {
      const int v0 = w*32 + 2*j, v1 = v0 + 1;
      const float* wr0 = wl + v0*T3;   // uniform -> s_load
      const float* wr1 = wl + v1*T3;
      float a0 = bl[v0], a1 = bl[v1];
      #pragma unroll
      for (int t = 0; t < T3; ++t) {
        a0 += orow[t] * wr0[t];
        a1 += orow[t] * wr1[t];
      }
      if (a0 > best) { best = a0; bidx = v0; }
      if (a1 > best) { best = a1; bidx = v1; }
    }
    if (lane < 32) { candv[w][q] = best; candi[w][q] = bidx; }
  }
  __syncthreads();
  if (tid < 32) {
    float b = candv[0][tid]; int bi = candi[0][tid];
    #pragma unroll
    for (int ww = 1; ww < 4; ++ww) {   // ascending v-range: strict > keeps
      float cv = candv[ww][tid];       // first max (jnp.argmax tie-break)
      int   ci = candi[ww][tid];
      if (cv > b) { b = cv; bi = ci; }
    }
    out[s*BB + tid] = (float)bi;
  }
}

extern "C" void kernel_launch(void* const* d_in, const int* in_sizes, int n_in,
                              void* d_out, int out_size, void* d_ws, size_t ws_size,
                              hipStream_t stream)
{
  const int*   tokens = (const int*)  d_in[0];
  const float* emb    = (const float*)d_in[1];
  const float* pos    = (const float*)d_in[2];
  const float* gamma  = (const float*)d_in[3];
  const float* beta   = (const float*)d_in[4];
  const float* w1     = (const float*)d_in[5];
  const float* b1     = (const float*)d_in[6];
  const float* w2     = (const float*)d_in[7];
  const float* b2     = (const float*)d_in[8];
  const float* w3     = (const float*)d_in[9];
  const float* b3     = (const float*)d_in[10];
  const float* wl     = (const float*)d_in[11];
  const float* bl     = (const float*)d_in[12];
  float* out = (float*)d_out;

  double* rowsumd = (double*)d_ws;            // 2048
  double* rowsqd  = rowsumd + NSTAT;          // 2048
  float*  part    = (float*)(rowsqd + NSTAT); // 4*64*16*114

  k_main<<<dim3(SS, 4), dim3(256), 0, stream>>>(
      tokens, emb, pos, w1, rowsumd, rowsqd, part);
  k_tail<<<dim3(SS), dim3(256), 0, stream>>>(
      rowsumd, rowsqd, gamma, beta, part, w1, b1, w2, b2, w3, b3,
      wl, bl, out);
}

// Round 10
// 198.122 us; speedup vs baseline: 1.1480x; 1.0373x over previous
//
#include <hip/hip_runtime.h>
#include <math.h>

#define SS 64
#define BB 32
#define DD 586
#define DE 583      // emb columns
#define U1 114      // length after conv1+pool1
#define U2 38       // after pool2
#define T3 36       // conv3 out length
#define NTOK 18752  // B*D elements per s
#define NSTAT (SS*BB)
#define SQD 24.207436873820409f  // sqrt(586)

// ws layout:
//   double rowsumd[2048]; double rowsqd[2048];
//   float  part[4][64][16][114];   // raw conv1+pool1 partials (no affine)

// ---- K1: gather once -> row stats + raw fused conv1+avgpool(5) ----
// (identical to R6's proven k_main)
__global__ __launch_bounds__(256) void k_main(
    const int* __restrict__ tokens, const float* __restrict__ emb,
    const float* __restrict__ pos, const float* __restrict__ w1,
    double* __restrict__ rowsumd, double* __restrict__ rowsqd,
    float* __restrict__ part)
{
  const int s = blockIdx.x, g = blockIdx.y;
  const int tid = threadIdx.x;
  __shared__ float xs[8*DD];
  __shared__ int stok[8];
  if (tid < 8) stok[tid] = tokens[s*BB + g*8 + tid];
  __syncthreads();
  {
    const int rr = tid >> 5, l = tid & 31;
    const float* row = emb + (size_t)stok[rr]*DE;
    double sum = 0.0, sq = 0.0;
    #pragma unroll
    for (int j = 0; j < 19; ++j) {
      int d = l + 32*j;
      if (d < DD) {
        float v = (d < DE) ? row[d] * SQD
                           : pos[(s*BB + g*8 + rr)*3 + (d - DE)];
        xs[rr*DD + d] = v;
        sum += v; sq += (double)v*v;
      }
    }
    for (int off = 16; off > 0; off >>= 1) {
      sum += __shfl_down(sum, off, 32);
      sq  += __shfl_down(sq, off, 32);
    }
    if (l == 0) {
      rowsumd[s*BB + g*8 + rr] = sum;
      rowsqd [s*BB + g*8 + rr] = sq;
    }
  }
  __syncthreads();
  const int up = tid & 127;
  const int oh = __builtin_amdgcn_readfirstlane(tid >> 7);  // wave-uniform
  const int u  = (up < U1) ? up : (U1 - 1);
  float acc[8] = {0,0,0,0,0,0,0,0};
  for (int cc = 0; cc < 8; ++cc) {
    const float* xr = &xs[cc*DD + 5*u];   // stride-5: conflict-free
    float xv[21];
    #pragma unroll
    for (int m = 0; m < 21; ++m) xv[m] = xr[m];
    float xw[17];
    #pragma unroll
    for (int k = 0; k < 17; ++k)
      xw[k] = ((xv[k] + xv[k+1]) + (xv[k+2] + xv[k+3])) + xv[k+4];
    #pragma unroll
    for (int j = 0; j < 8; ++j) {
      const float* wj = w1 + ((size_t)(oh*8 + j)*BB + (g*8 + cc))*17;
      float a = 0.f;
      #pragma unroll
      for (int k = 0; k < 17; ++k) a += xw[k] * wj[k];
      acc[j] += a;
    }
  }
  if (up < U1) {
    float* pb = part + ((size_t)(g*SS + s)*16 + oh*8)*U1 + up;
    #pragma unroll
    for (int j = 0; j < 8; ++j) pb[j*U1] = acc[j] * 0.2f;  // coalesced
  }
}

// ---- K2: stats -> affine assembly, pool2, conv2, conv3, dense, argmax ----
// Identical to R6's k_tail except the dense loop caches the thread's o5 row
// in 36 VGPRs (q is fixed per thread), halving dense LDS traffic.
__global__ __launch_bounds__(256) void k_tail(
    const double* __restrict__ rowsumd, const double* __restrict__ rowsqd,
    const float* __restrict__ gamma, const float* __restrict__ beta,
    const float* __restrict__ part, const float* __restrict__ w1,
    const float* __restrict__ b1, const float* __restrict__ w2,
    const float* __restrict__ b2, const float* __restrict__ w3,
    const float* __restrict__ b3, const float* __restrict__ wl,
    const float* __restrict__ bl, float* __restrict__ out)
{
  const int s = blockIdx.x, tid = threadIdx.x;
  __shared__ float o2[16*U1];
  __shared__ float p2[16*U2];
  __shared__ float o4[8*U2];
  __shared__ float o5[32*T3];
  __shared__ float wlb[128*37];   // +1 pad: conflict-free
  __shared__ float blb[128];
  __shared__ float wsumb[16];
  __shared__ float sAl, sDe;
  for (int idx = tid; idx < 128*36; idx += 256) {
    int v = idx / 36, t = idx - v*36;
    wlb[v*37 + t] = wl[idx];
  }
  if (tid < 128) blb[tid] = bl[tid];
  // wsum[o] = sum of 544 contiguous w1 floats
  {
    const int o = tid >> 4, i = tid & 15;
    float acc = 0.f;
    for (int j = i; j < BB*17; j += 16) acc += w1[o*BB*17 + j];
    for (int off = 8; off > 0; off >>= 1) acc += __shfl_down(acc, off, 16);
    if (i == 0) wsumb[o] = acc;
  }
  // deterministic stats reduce (32 doubles, fixed tree) -> al, de
  if (tid < 32) {
    double sm = rowsumd[s*BB + tid], qq = rowsqd[s*BB + tid];
    for (int off = 16; off > 0; off >>= 1) {
      sm += __shfl_down(sm, off, 32);
      qq += __shfl_down(qq, off, 32);
    }
    if (tid == 0) {
      double m0d = sm / (double)NTOK;
      float m0 = (float)m0d;
      float v0 = (float)(qq / (double)NTOK - m0d*m0d);
      float a = 1.0f;
      for (int l = 0; l < 4; ++l) {
        float r = 1.0f / sqrtf(a*a*v0 + 1e-5f);
        a = gamma[l*SS + s] * r * a;
      }
      sAl = a;
      sDe = beta[3*SS + s] - a*m0;
    }
  }
  __syncthreads();
  const float al = sAl, de = sDe;
  for (int idx = tid; idx < 16*U1; idx += 256) {
    int o = idx / U1;
    float psum = part[(size_t)(0*SS + s)*16*U1 + idx]
               + part[(size_t)(1*SS + s)*16*U1 + idx]
               + part[(size_t)(2*SS + s)*16*U1 + idx]
               + part[(size_t)(3*SS + s)*16*U1 + idx];
    o2[idx] = al*psum + de*wsumb[o] + b1[o];
  }
  __syncthreads();
  for (int i2 = tid; i2 < 16*U2; i2 += 256) {   // 608 > 256: loop required
    int o = i2 / U2, v = i2 - o*U2;
    p2[i2] = (o2[o*U1 + 3*v] + o2[o*U1 + 3*v+1] + o2[o*U1 + 3*v+2]) * (1.f/3.f);
  }
  __syncthreads();
  for (int i2 = tid; i2 < 8*U2; i2 += 256) {    // 304 > 256: loop required
    int p = i2 / U2, v = i2 - p*U2;
    float a2 = b2[p];
    #pragma unroll
    for (int o = 0; o < 16; ++o) a2 += p2[o*U2 + v] * w2[p*16 + o];
    o4[i2] = a2;
  }
  __syncthreads();
  for (int i2 = tid; i2 < 32*T3; i2 += 256) {   // 1152 > 256: loop required
    int q = i2 / T3, t = i2 - q*T3;
    float a3 = b3[q];
    #pragma unroll
    for (int p = 0; p < 8; ++p) {
      a3 += o4[p*U2 + t    ] * w3[(q*8+p)*3 + 0]
          + o4[p*U2 + t + 1] * w3[(q*8+p)*3 + 1]
          + o4[p*U2 + t + 2] * w3[(q*8+p)*3 + 2];
    }
    o5[i2] = a3;
  }
  __syncthreads();
  // 256 threads: q = tid>>3 covers 0..31, vs = tid&7; v = vs + 8*i ascending
  // per thread; (max,min-idx) merge preserves first-max tie-break.
  // orow cached in 36 VGPRs (loop-invariant over v) -> dense LDS halved.
  const int q = tid >> 3, vs = tid & 7;
  float orow[T3];
  #pragma unroll
  for (int t = 0; t < T3; ++t) orow[t] = o5[q*T3 + t];
  float best = -1e30f; int bidx = 0;
  for (int i = 0; i < 16; ++i) {
    int v = vs + 8*i;
    float acc = blb[v];
    const float* wr = &wlb[v*37];
    #pragma unroll
    for (int t = 0; t < 36; ++t) acc += orow[t] * wr[t];
    if (acc > best) { best = acc; bidx = v; }
  }
  #pragma unroll
  for (int off = 1; off < 8; off <<= 1) {
    float ov = __shfl_xor(best, off);
    int oi = __shfl_xor(bidx, off);
    if (ov > best || (ov == best && oi < bidx)) { best = ov; bidx = oi; }
  }
  if (vs == 0) out[s*BB + q] = (float)bidx;
}

extern "C" void kernel_launch(void* const* d_in, const int* in_sizes, int n_in,
                              void* d_out, int out_size, void* d_ws, size_t ws_size,
                              hipStream_t stream)
{
  const int*   tokens = (const int*)  d_in[0];
  const float* emb    = (const float*)d_in[1];
  const float* pos    = (const float*)d_in[2];
  const float* gamma  = (const float*)d_in[3];
  const float* beta   = (const float*)d_in[4];
  const float* w1     = (const float*)d_in[5];
  const float* b1     = (const float*)d_in[6];
  const float* w2     = (const float*)d_in[7];
  const float* b2     = (const float*)d_in[8];
  const float* w3     = (const float*)d_in[9];
  const float* b3     = (const float*)d_in[10];
  const float* wl     = (const float*)d_in[11];
  const float* bl     = (const float*)d_in[12];
  float* out = (float*)d_out;

  double* rowsumd = (double*)d_ws;            // 2048
  double* rowsqd  = rowsumd + NSTAT;          // 2048
  float*  part    = (float*)(rowsqd + NSTAT); // 4*64*16*114

  k_main<<<dim3(SS, 4), dim3(256), 0, stream>>>(
      tokens, emb, pos, w1, rowsumd, rowsqd, part);
  k_tail<<<dim3(SS), dim3(256), 0, stream>>>(
      rowsumd, rowsqd, gamma, beta, part, w1, b1, w2, b2, w3, b3,
      wl, bl, out);
}

// Round 11
// 194.405 us; speedup vs baseline: 1.1699x; 1.0191x over previous
//
#include <hip/hip_runtime.h>
#include <math.h>

#define SS 64
#define BB 32
#define DD 586
#define DE 583      // emb columns
#define U1 114      // length after conv1+pool1
#define U2 38       // after pool2
#define T3 36       // conv3 out length
#define NTOK 18752  // B*D elements per s
#define NSTAT (SS*BB)
#define SQD 24.207436873820409f  // sqrt(586)

// ws layout:
//   double rowsumd[2048]; double rowsqd[2048];
//   float  part[4][64][16][114];   // raw conv1+pool1 partials (no affine)

// ---- K1: gather once -> row stats + raw fused conv1+avgpool(5) ----
// Deferred affine: conv(al*x+de) = al*conv(x) + de*wsum; conv runs on RAW x,
// stats come from the SAME staged tile (single gather).
// Conv identity: out_raw[o,u] = 0.2 * sum_{c,k} w1[o,c,k] * xw[c,k],
//   xw[c,k] = sum_{m=k..k+4} x[c,5u+m]   (k=0..16)
__global__ __launch_bounds__(256) void k_main(
    const int* __restrict__ tokens, const float* __restrict__ emb,
    const float* __restrict__ pos, const float* __restrict__ w1,
    double* __restrict__ rowsumd, double* __restrict__ rowsqd,
    float* __restrict__ part)
{
  const int s = blockIdx.x, g = blockIdx.y;
  const int tid = threadIdx.x;
  __shared__ float xs[8*DD];
  __shared__ int stok[8];
  if (tid < 8) stok[tid] = tokens[s*BB + g*8 + tid];
  __syncthreads();
  {
    const int rr = tid >> 5, l = tid & 31;
    const float* row = emb + (size_t)stok[rr]*DE;
    double sum = 0.0, sq = 0.0;
    #pragma unroll
    for (int j = 0; j < 19; ++j) {
      int d = l + 32*j;
      if (d < DD) {
        float v = (d < DE) ? row[d] * SQD
                           : pos[(s*BB + g*8 + rr)*3 + (d - DE)];
        xs[rr*DD + d] = v;
        sum += v; sq += (double)v*v;
      }
    }
    for (int off = 16; off > 0; off >>= 1) {
      sum += __shfl_down(sum, off, 32);
      sq  += __shfl_down(sq, off, 32);
    }
    if (l == 0) {
      rowsumd[s*BB + g*8 + rr] = sum;
      rowsqd [s*BB + g*8 + rr] = sq;
    }
  }
  __syncthreads();
  const int up = tid & 127;
  const int oh = __builtin_amdgcn_readfirstlane(tid >> 7);  // wave-uniform
  const int u  = (up < U1) ? up : (U1 - 1);
  float acc[8] = {0,0,0,0,0,0,0,0};
  for (int cc = 0; cc < 8; ++cc) {
    const float* xr = &xs[cc*DD + 5*u];   // stride-5: conflict-free
    float xv[21];
    #pragma unroll
    for (int m = 0; m < 21; ++m) xv[m] = xr[m];
    float xw[17];
    #pragma unroll
    for (int k = 0; k < 17; ++k)
      xw[k] = ((xv[k] + xv[k+1]) + (xv[k+2] + xv[k+3])) + xv[k+4];
    #pragma unroll
    for (int j = 0; j < 8; ++j) {
      const float* wj = w1 + ((size_t)(oh*8 + j)*BB + (g*8 + cc))*17;
      float a = 0.f;
      #pragma unroll
      for (int k = 0; k < 17; ++k) a += xw[k] * wj[k];
      acc[j] += a;
    }
  }
  if (up < U1) {
    float* pb = part + ((size_t)(g*SS + s)*16 + oh*8)*U1 + up;
    #pragma unroll
    for (int j = 0; j < 8; ++j) pb[j*U1] = acc[j] * 0.2f;  // coalesced
  }
}

// ---- K2: stats -> affine assembly, pool2, conv2, conv3, dense, argmax ----
// (exact R6 configuration — best measured: 193.5 us)
__global__ __launch_bounds__(256) void k_tail(
    const double* __restrict__ rowsumd, const double* __restrict__ rowsqd,
    const float* __restrict__ gamma, const float* __restrict__ beta,
    const float* __restrict__ part, const float* __restrict__ w1,
    const float* __restrict__ b1, const float* __restrict__ w2,
    const float* __restrict__ b2, const float* __restrict__ w3,
    const float* __restrict__ b3, const float* __restrict__ wl,
    const float* __restrict__ bl, float* __restrict__ out)
{
  const int s = blockIdx.x, tid = threadIdx.x;
  __shared__ float o2[16*U1];
  __shared__ float p2[16*U2];
  __shared__ float o4[8*U2];
  __shared__ float o5[32*T3];
  __shared__ float wlb[128*37];   // +1 pad: conflict-free
  __shared__ float blb[128];
  __shared__ float wsumb[16];
  __shared__ float sAl, sDe;
  for (int idx = tid; idx < 128*36; idx += 256) {
    int v = idx / 36, t = idx - v*36;
    wlb[v*37 + t] = wl[idx];
  }
  if (tid < 128) blb[tid] = bl[tid];
  // wsum[o] = sum of 544 contiguous w1 floats
  {
    const int o = tid >> 4, i = tid & 15;
    float acc = 0.f;
    for (int j = i; j < BB*17; j += 16) acc += w1[o*BB*17 + j];
    for (int off = 8; off > 0; off >>= 1) acc += __shfl_down(acc, off, 16);
    if (i == 0) wsumb[o] = acc;
  }
  // deterministic stats reduce (32 doubles, fixed tree) -> al, de
  if (tid < 32) {
    double sm = rowsumd[s*BB + tid], qq = rowsqd[s*BB + tid];
    for (int off = 16; off > 0; off >>= 1) {
      sm += __shfl_down(sm, off, 32);
      qq += __shfl_down(qq, off, 32);
    }
    if (tid == 0) {
      double m0d = sm / (double)NTOK;
      float m0 = (float)m0d;
      float v0 = (float)(qq / (double)NTOK - m0d*m0d);
      float a = 1.0f;
      for (int l = 0; l < 4; ++l) {
        float r = 1.0f / sqrtf(a*a*v0 + 1e-5f);
        a = gamma[l*SS + s] * r * a;
      }
      sAl = a;
      sDe = beta[3*SS + s] - a*m0;
    }
  }
  __syncthreads();
  const float al = sAl, de = sDe;
  for (int idx = tid; idx < 16*U1; idx += 256) {
    int o = idx / U1;
    float psum = part[(size_t)(0*SS + s)*16*U1 + idx]
               + part[(size_t)(1*SS + s)*16*U1 + idx]
               + part[(size_t)(2*SS + s)*16*U1 + idx]
               + part[(size_t)(3*SS + s)*16*U1 + idx];
    o2[idx] = al*psum + de*wsumb[o] + b1[o];
  }
  __syncthreads();
  for (int i2 = tid; i2 < 16*U2; i2 += 256) {   // 608 > 256: loop required
    int o = i2 / U2, v = i2 - o*U2;
    p2[i2] = (o2[o*U1 + 3*v] + o2[o*U1 + 3*v+1] + o2[o*U1 + 3*v+2]) * (1.f/3.f);
  }
  __syncthreads();
  for (int i2 = tid; i2 < 8*U2; i2 += 256) {    // 304 > 256: loop required
    int p = i2 / U2, v = i2 - p*U2;
    float a2 = b2[p];
    #pragma unroll
    for (int o = 0; o < 16; ++o) a2 += p2[o*U2 + v] * w2[p*16 + o];
    o4[i2] = a2;
  }
  __syncthreads();
  for (int i2 = tid; i2 < 32*T3; i2 += 256) {   // 1152 > 256: loop required
    int q = i2 / T3, t = i2 - q*T3;
    float a3 = b3[q];
    #pragma unroll
    for (int p = 0; p < 8; ++p) {
      a3 += o4[p*U2 + t    ] * w3[(q*8+p)*3 + 0]
          + o4[p*U2 + t + 1] * w3[(q*8+p)*3 + 1]
          + o4[p*U2 + t + 2] * w3[(q*8+p)*3 + 2];
    }
    o5[i2] = a3;
  }
  __syncthreads();
  // 256 threads: q = tid>>3 covers 0..31, vs = tid&7; v = vs + 8*i ascending
  // per thread; (max,min-idx) merge preserves first-max tie-break.
  const int q = tid >> 3, vs = tid & 7;
  float best = -1e30f; int bidx = 0;
  const float* orow = &o5[q*T3];
  for (int i = 0; i < 16; ++i) {
    int v = vs + 8*i;
    float acc = blb[v];
    const float* wr = &wlb[v*37];
    #pragma unroll
    for (int t = 0; t < 36; ++t) acc += orow[t] * wr[t];
    if (acc > best) { best = acc; bidx = v; }
  }
  #pragma unroll
  for (int off = 1; off < 8; off <<= 1) {
    float ov = __shfl_xor(best, off);
    int oi = __shfl_xor(bidx, off);
    if (ov > best || (ov == best && oi < bidx)) { best = ov; bidx = oi; }
  }
  if (vs == 0) out[s*BB + q] = (float)bidx;
}

extern "C" void kernel_launch(void* const* d_in, const int* in_sizes, int n_in,
                              void* d_out, int out_size, void* d_ws, size_t ws_size,
                              hipStream_t stream)
{
  const int*   tokens = (const int*)  d_in[0];
  const float* emb    = (const float*)d_in[1];
  const float* pos    = (const float*)d_in[2];
  const float* gamma  = (const float*)d_in[3];
  const float* beta   = (const float*)d_in[4];
  const float* w1     = (const float*)d_in[5];
  const float* b1     = (const float*)d_in[6];
  const float* w2     = (const float*)d_in[7];
  const float* b2     = (const float*)d_in[8];
  const float* w3     = (const float*)d_in[9];
  const float* b3     = (const float*)d_in[10];
  const float* wl     = (const float*)d_in[11];
  const float* bl     = (const float*)d_in[12];
  float* out = (float*)d_out;

  double* rowsumd = (double*)d_ws;            // 2048
  double* rowsqd  = rowsumd + NSTAT;          // 2048
  float*  part    = (float*)(rowsqd + NSTAT); // 4*64*16*114

  k_main<<<dim3(SS, 4), dim3(256), 0, stream>>>(
      tokens, emb, pos, w1, rowsumd, rowsqd, part);
  k_tail<<<dim3(SS), dim3(256), 0, stream>>>(
      rowsumd, rowsqd, gamma, beta, part, w1, b1, w2, b2, w3, b3,
      wl, bl, out);
}